// Round 5
// baseline (970.166 us; speedup 1.0000x reference)
//
#include <hip/hip_runtime.h>
#include <math.h>

#define L0_TOK 365
#define L1_TOK 366
#define L_TOT  732   // 365 + 366 + 1
#define NH     32
#define XSTR   16    // words per token row in LDS (16 bf16x2, no pad)

// LDS offsets for embed weights (floats)
#define E0W1 0
#define E0B1 256
#define E0W2 288
#define E0B2 1312
#define E1W1 1344
#define E1B1 1856
#define E1W2 1888
#define E1B2 2912
#define NWE  2944

// LDS offsets for pipeline weights (floats)
#define PF1W1 0
#define PF1B1 1024
#define PF1W2 1056
#define PF1B2 2080
#define PF2W1 2112
#define PF2B1 3136
#define PF2W2 3168
#define PLN1G 3200
#define PLN1B 3232
#define PLN2G 3264
#define PLN2B 3296
#define PF2B2 3328
#define NWP   3329

__device__ __forceinline__ unsigned pack_bf16x2(float a, float b) {
    unsigned ua = __float_as_uint(a), ub = __float_as_uint(b);
    ua = (ua + 0x7fffu + ((ua >> 16) & 1u)) >> 16;
    ub = (ub + 0x7fffu + ((ub >> 16) & 1u)) >> 16;
    return ua | (ub << 16);
}
__device__ __forceinline__ float bf_lo(unsigned w) { return __uint_as_float(w << 16); }
__device__ __forceinline__ float bf_hi(unsigned w) { return __uint_as_float(w & 0xffff0000u); }
__device__ __forceinline__ float4 lds4(const float* p) { return *((const float4*)p); }

// Embed token l of batch b -> x[32] fp32. e0/e1 weights come from LDS (We),
// ec weights (token 731 only) from global. Straight-line (one token/thread).
__device__ __forceinline__ void embed_token_lds(
    int b, int l, const float* __restrict__ We,
    const float* __restrict__ x0, const float* __restrict__ x1,
    const float* __restrict__ pos0, const float* __restrict__ pos1,
    const float* __restrict__ xcT,
    const float* __restrict__ ecw1, const float* __restrict__ ecb1,
    const float* __restrict__ ecw2, const float* __restrict__ ecb2,
    float x[NH])
{
    float h[NH];
    if (l < L0_TOK) {
        const float4* p = (const float4*)(x0 + ((size_t)b * L0_TOK + l) * 8);
        float4 i0 = p[0], i1 = p[1];
        #pragma unroll
        for (int o = 0; o < NH; o++) {
            float a = We[E0B1 + o];
            float4 wa = lds4(We + E0W1 + o * 8);
            float4 wb = lds4(We + E0W1 + o * 8 + 4);
            a = fmaf(wa.x, i0.x, a); a = fmaf(wa.y, i0.y, a);
            a = fmaf(wa.z, i0.z, a); a = fmaf(wa.w, i0.w, a);
            a = fmaf(wb.x, i1.x, a); a = fmaf(wb.y, i1.y, a);
            a = fmaf(wb.z, i1.z, a); a = fmaf(wb.w, i1.w, a);
            h[o] = fmaxf(a, 0.f);
        }
        #pragma unroll
        for (int o = 0; o < NH; o++) {
            float a = We[E0B2 + o];
            #pragma unroll
            for (int q = 0; q < 8; q++) {
                float4 w = lds4(We + E0W2 + o * NH + 4 * q);
                a = fmaf(w.x, h[4*q+0], a); a = fmaf(w.y, h[4*q+1], a);
                a = fmaf(w.z, h[4*q+2], a); a = fmaf(w.w, h[4*q+3], a);
            }
            x[o] = a;
        }
        float pv = pos0[(size_t)b * L0_TOK + l];
        #pragma unroll
        for (int i = 0; i < NH / 2; i++) {
            float ang = pv * (3.14159265358979323846f / (float)(i + 1));
            x[2 * i]     += __sinf(ang);
            x[2 * i + 1] += __cosf(ang);
        }
    } else if (l < L0_TOK + L1_TOK) {
        int ll = l - L0_TOK;
        const float4* p = (const float4*)(x1 + ((size_t)b * L1_TOK + ll) * 16);
        float4 i0 = p[0], i1 = p[1], i2 = p[2], i3 = p[3];
        float in[16] = {i0.x,i0.y,i0.z,i0.w, i1.x,i1.y,i1.z,i1.w,
                        i2.x,i2.y,i2.z,i2.w, i3.x,i3.y,i3.z,i3.w};
        #pragma unroll
        for (int o = 0; o < NH; o++) {
            float a = We[E1B1 + o];
            #pragma unroll
            for (int q = 0; q < 4; q++) {
                float4 w = lds4(We + E1W1 + o * 16 + 4 * q);
                a = fmaf(w.x, in[4*q+0], a); a = fmaf(w.y, in[4*q+1], a);
                a = fmaf(w.z, in[4*q+2], a); a = fmaf(w.w, in[4*q+3], a);
            }
            h[o] = fmaxf(a, 0.f);
        }
        #pragma unroll
        for (int o = 0; o < NH; o++) {
            float a = We[E1B2 + o];
            #pragma unroll
            for (int q = 0; q < 8; q++) {
                float4 w = lds4(We + E1W2 + o * NH + 4 * q);
                a = fmaf(w.x, h[4*q+0], a); a = fmaf(w.y, h[4*q+1], a);
                a = fmaf(w.z, h[4*q+2], a); a = fmaf(w.w, h[4*q+3], a);
            }
            x[o] = a;
        }
        float pv = pos1[(size_t)b * L1_TOK + ll];
        #pragma unroll
        for (int i = 0; i < NH / 2; i++) {
            float ang = pv * (3.14159265358979323846f / (float)(i + 1));
            x[2 * i]     += __sinf(ang);
            x[2 * i + 1] += __cosf(ang);
        }
    } else {
        float in[NH];
        const float* p = xcT + (size_t)b * NH;
        #pragma unroll
        for (int i = 0; i < NH; i++) in[i] = p[i];
        #pragma unroll
        for (int o = 0; o < NH; o++) {
            float a = ecb1[o];
            #pragma unroll
            for (int i = 0; i < NH; i++) a = fmaf(ecw1[o * NH + i], in[i], a);
            h[o] = fmaxf(a, 0.f);
        }
        #pragma unroll
        for (int o = 0; o < NH; o++) {
            float a = ecb2[o];
            #pragma unroll
            for (int j = 0; j < NH; j++) a = fmaf(ecw2[o * NH + j], h[j], a);
            x[o] = a;
        }
    }
}

__device__ __forceinline__ void stage_embed_weights(
    int tid, int nthreads, float* We,
    const float* __restrict__ e0w1, const float* __restrict__ e0b1,
    const float* __restrict__ e0w2, const float* __restrict__ e0b2,
    const float* __restrict__ e1w1, const float* __restrict__ e1b1,
    const float* __restrict__ e1w2, const float* __restrict__ e1b2)
{
    for (int i = tid; i < NWE; i += nthreads) {
        float v;
        if      (i < E0B1) v = e0w1[i - E0W1];
        else if (i < E0W2) v = e0b1[i - E0B1];
        else if (i < E0B2) v = e0w2[i - E0W2];
        else if (i < E1W1) v = e0b2[i - E0B2];
        else if (i < E1B1) v = e1w1[i - E1W1];
        else if (i < E1W2) v = e1b1[i - E1B1];
        else if (i < E1B2) v = e1w2[i - E1W2];
        else               v = e1b2[i - E1B2];
        We[i] = v;
    }
}

// =================== Kernel A: embed + Gram + attention collapse ===========
// 768 threads (12 waves), one token per thread. LDS ~62.7 KB -> 1 WG/CU,
// min 3 waves/EU -> VGPR cap 170 (deep load batching, chain ILP).
__global__ __launch_bounds__(768, 3) void kernelA(
    const float* __restrict__ x0,  const float* __restrict__ x1,
    const float* __restrict__ pos0,const float* __restrict__ pos1,
    const float* __restrict__ xcT,
    const float* __restrict__ e0w1,const float* __restrict__ e0b1,
    const float* __restrict__ e0w2,const float* __restrict__ e0b2,
    const float* __restrict__ e1w1,const float* __restrict__ e1b1,
    const float* __restrict__ e1w2,const float* __restrict__ e1b2,
    const float* __restrict__ ecw1,const float* __restrict__ ecb1,
    const float* __restrict__ ecw2,const float* __restrict__ ecb2,
    const float* __restrict__ wq,  const float* __restrict__ wk,
    const float* __restrict__ wv,  const float* __restrict__ wo,
    float* __restrict__ wbout)                   // [B][1024]
{
    const int b   = blockIdx.x;
    const int tid = threadIdx.x;

    __shared__ unsigned Xs[L_TOT * XSTR];   // 46.8 KB; T1/T2 alias this after Gram
    __shared__ float Cm[NH * NH];           // 4 KB
    __shared__ float We[NWE];               // 11.5 KB

    stage_embed_weights(tid, 768, We, e0w1, e0b1, e0w2, e0b2,
                        e1w1, e1b1, e1w2, e1b2);
    for (int i = tid; i < NH * NH; i += 768) Cm[i] = 0.f;
    __syncthreads();

    // ---- embed: one token per thread ----
    if (tid < L_TOT) {
        float xv[NH];
        embed_token_lds(b, tid, We, x0, x1, pos0, pos1, xcT,
                        ecw1, ecb1, ecw2, ecb2, xv);
        uint4 w0, w1, w2, w3;
        w0.x = pack_bf16x2(xv[0], xv[1]);  w0.y = pack_bf16x2(xv[2], xv[3]);
        w0.z = pack_bf16x2(xv[4], xv[5]);  w0.w = pack_bf16x2(xv[6], xv[7]);
        w1.x = pack_bf16x2(xv[8], xv[9]);  w1.y = pack_bf16x2(xv[10], xv[11]);
        w1.z = pack_bf16x2(xv[12], xv[13]);w1.w = pack_bf16x2(xv[14], xv[15]);
        w2.x = pack_bf16x2(xv[16], xv[17]);w2.y = pack_bf16x2(xv[18], xv[19]);
        w2.z = pack_bf16x2(xv[20], xv[21]);w2.w = pack_bf16x2(xv[22], xv[23]);
        w3.x = pack_bf16x2(xv[24], xv[25]);w3.y = pack_bf16x2(xv[26], xv[27]);
        w3.z = pack_bf16x2(xv[28], xv[29]);w3.w = pack_bf16x2(xv[30], xv[31]);
        uint4* dst = (uint4*)&Xs[tid * XSTR];
        dst[0] = w0; dst[1] = w1; dst[2] = w2; dst[3] = w3;
    }
    __syncthreads();

    // ---- Gram C = sum_l x_l x_l^T : 12 waves x 61 tokens, 4x4 lane tiles ----
    {
        const int wvid = tid >> 6, lane = tid & 63;
        const int r = lane >> 3, c = lane & 7;
        const int lbeg = 61 * wvid;
        const int lend = lbeg + 61;
        float acc[4][4];
        #pragma unroll
        for (int i = 0; i < 4; i++)
            #pragma unroll
            for (int j = 0; j < 4; j++) acc[i][j] = 0.f;
        for (int l = lbeg; l < lend; l++) {
            uint2 wr = *((const uint2*)&Xs[l * XSTR + 2 * r]);
            uint2 wc = *((const uint2*)&Xs[l * XSTR + 2 * c]);
            float av[4] = {bf_lo(wr.x), bf_hi(wr.x), bf_lo(wr.y), bf_hi(wr.y)};
            float bv[4] = {bf_lo(wc.x), bf_hi(wc.x), bf_lo(wc.y), bf_hi(wc.y)};
            #pragma unroll
            for (int i = 0; i < 4; i++)
                #pragma unroll
                for (int j = 0; j < 4; j++)
                    acc[i][j] = fmaf(av[i], bv[j], acc[i][j]);
        }
        #pragma unroll
        for (int i = 0; i < 4; i++)
            #pragma unroll
            for (int j = 0; j < 4; j++)
                atomicAdd(&Cm[(4 * r + i) * NH + 4 * c + j], acc[i][j]);
    }
    __syncthreads();

    // ---- attention collapse (T1/T2 alias the now-dead Xs) ----
    float* T1 = (float*)Xs;
    float* T2 = (float*)(Xs + 1024);

    for (int idx = tid; idx < NH * NH; idx += 768) {
        int i = idx >> 5, g = idx & 31;
        float a = 0.f;
        #pragma unroll
        for (int j = 0; j < NH; j++) a = fmaf(Cm[i * NH + j], wk[g * NH + j], a);
        T1[i * NH + g] = a;
    }
    __syncthreads();
    const float rsL = 1.0f / sqrtf((float)L_TOT);
    for (int idx = tid; idx < NH * NH; idx += 768) {
        int h = idx >> 5, g = idx & 31;
        float a = 0.f;
        #pragma unroll
        for (int i = 0; i < NH; i++) a = fmaf(wq[h * NH + i], T1[i * NH + g], a);
        T2[h * NH + g] = a * rsL;
    }
    __syncthreads();
    if (tid < NH) {
        const int h = tid;
        float mx = -1e30f;
        #pragma unroll
        for (int g = 0; g < NH; g++) mx = fmaxf(mx, T2[h * NH + g]);
        float s = 0.f;
        #pragma unroll
        for (int g = 0; g < NH; g++) {
            float e = __expf(T2[h * NH + g] - mx);
            T2[h * NH + g] = e; s += e;
        }
        float inv = 1.f / s;
        #pragma unroll
        for (int g = 0; g < NH; g++) T2[h * NH + g] *= inv;
    }
    __syncthreads();
    for (int idx = tid; idx < NH * NH; idx += 768) {
        int h = idx >> 5, j = idx & 31;
        float a = 0.f;
        #pragma unroll
        for (int g = 0; g < NH; g++) a = fmaf(T2[h * NH + g], wv[g * NH + j], a);
        T1[h * NH + j] = a;
    }
    __syncthreads();
    for (int idx = tid; idx < NH * NH; idx += 768) {
        int o = idx >> 5, j = idx & 31;
        float a = 0.f;
        #pragma unroll
        for (int h = 0; h < NH; h++) a = fmaf(wo[o * NH + h], T1[h * NH + j], a);
        wbout[(size_t)b * (NH * NH) + o * NH + j] = a;
    }
}

// =================== Kernel B: per-token pipeline ==========================
// grid (B, 3), 256 threads, one token per thread. All weights in LDS.
__global__ __launch_bounds__(256, 4) void kernelB(
    const float* __restrict__ x0,  const float* __restrict__ x1,
    const float* __restrict__ pos0,const float* __restrict__ pos1,
    const float* __restrict__ xcT,
    const float* __restrict__ e0w1,const float* __restrict__ e0b1,
    const float* __restrict__ e0w2,const float* __restrict__ e0b2,
    const float* __restrict__ e1w1,const float* __restrict__ e1b1,
    const float* __restrict__ e1w2,const float* __restrict__ e1b2,
    const float* __restrict__ ecw1,const float* __restrict__ ecb1,
    const float* __restrict__ ecw2,const float* __restrict__ ecb2,
    const float* __restrict__ wbin,              // [B][1024]
    const float* __restrict__ ln1g,const float* __restrict__ ln1b,
    const float* __restrict__ ln2g,const float* __restrict__ ln2b,
    const float* __restrict__ f1w1,const float* __restrict__ f1b1,
    const float* __restrict__ f1w2,const float* __restrict__ f1b2,
    const float* __restrict__ f2w1,const float* __restrict__ f2b1,
    const float* __restrict__ f2w2,const float* __restrict__ f2b2,
    float* __restrict__ part)                    // [B][3 chunks][3 segs]
{
    const int b   = blockIdx.x;
    const int c   = blockIdx.y;
    const int tid = threadIdx.x;
    const int l   = c * 244 + tid;
    const bool active = (tid < 244);

    __shared__ float We[NWE];     // embed weights (11.5 KB)
    __shared__ float Wp[NWP];     // pipeline weights (13 KB)
    __shared__ float wbs[NH*NH];  // per-batch attention matrix (4 KB)
    __shared__ float red[4 * 3];

    stage_embed_weights(tid, 256, We, e0w1, e0b1, e0w2, e0b2,
                        e1w1, e1b1, e1w2, e1b2);
    for (int i = tid; i < NWP; i += 256) {
        float v;
        if      (i < PF1B1) v = f1w1[i - PF1W1];
        else if (i < PF1W2) v = f1b1[i - PF1B1];
        else if (i < PF1B2) v = f1w2[i - PF1W2];
        else if (i < PF2W1) v = f1b2[i - PF1B2];
        else if (i < PF2B1) v = f2w1[i - PF2W1];
        else if (i < PF2W2) v = f2b1[i - PF2B1];
        else if (i < PLN1G) v = f2w2[i - PF2W2];
        else if (i < PLN1B) v = ln1g[i - PLN1G];
        else if (i < PLN2G) v = ln1b[i - PLN1B];
        else if (i < PLN2B) v = ln2g[i - PLN2G];
        else if (i < PF2B2) v = ln2b[i - PLN2B];
        else                v = f2b2[0];
        Wp[i] = v;
    }
    for (int i = tid; i < NH * NH; i += 256)
        wbs[i] = wbin[(size_t)b * (NH * NH) + i];
    __syncthreads();

    float y = 0.f;
    int seg = 2;
    if (active) {
        float x[NH];
        embed_token_lds(b, l, We, x0, x1, pos0, pos1, xcT,
                        ecw1, ecb1, ecw2, ecb2, x);

        // t = Wb @ x + x
        float t[NH];
        #pragma unroll
        for (int o = 0; o < NH; o++) {
            float a = x[o];
            #pragma unroll
            for (int q = 0; q < 8; q++) {
                float4 w = lds4(wbs + o * NH + 4 * q);
                a = fmaf(w.x, x[4*q+0], a); a = fmaf(w.y, x[4*q+1], a);
                a = fmaf(w.z, x[4*q+2], a); a = fmaf(w.w, x[4*q+3], a);
            }
            t[o] = a;
        }
        // LN1
        float m = 0.f;
        #pragma unroll
        for (int o = 0; o < NH; o++) m += t[o];
        m *= (1.f / 32.f);
        float vv = 0.f;
        #pragma unroll
        for (int o = 0; o < NH; o++) { float d = t[o] - m; vv = fmaf(d, d, vv); }
        vv *= (1.f / 32.f);
        float rs = rsqrtf(vv + 1e-5f);
        #pragma unroll
        for (int o = 0; o < NH; o++)
            t[o] = (t[o] - m) * rs * Wp[PLN1G + o] + Wp[PLN1B + o];

        // FFN1 layer1: u = relu(f1w1 @ t + b1)
        float u[NH];
        #pragma unroll
        for (int o = 0; o < NH; o++) {
            float a = Wp[PF1B1 + o];
            #pragma unroll
            for (int q = 0; q < 8; q++) {
                float4 w = lds4(Wp + PF1W1 + o * NH + 4 * q);
                a = fmaf(w.x, t[4*q+0], a); a = fmaf(w.y, t[4*q+1], a);
                a = fmaf(w.z, t[4*q+2], a); a = fmaf(w.w, t[4*q+3], a);
            }
            u[o] = fmaxf(a, 0.f);
        }
        // FFN1 layer2 + residual: t = f1w2 @ u + b2 + x
        #pragma unroll
        for (int o = 0; o < NH; o++) {
            float a = Wp[PF1B2 + o] + x[o];
            #pragma unroll
            for (int q = 0; q < 8; q++) {
                float4 w = lds4(Wp + PF1W2 + o * NH + 4 * q);
                a = fmaf(w.x, u[4*q+0], a); a = fmaf(w.y, u[4*q+1], a);
                a = fmaf(w.z, u[4*q+2], a); a = fmaf(w.w, u[4*q+3], a);
            }
            t[o] = a;
        }
        // LN2
        float m2 = 0.f;
        #pragma unroll
        for (int o = 0; o < NH; o++) m2 += t[o];
        m2 *= (1.f / 32.f);
        float v2 = 0.f;
        #pragma unroll
        for (int o = 0; o < NH; o++) { float d = t[o] - m2; v2 = fmaf(d, d, v2); }
        v2 *= (1.f / 32.f);
        float rs2 = rsqrtf(v2 + 1e-5f);
        #pragma unroll
        for (int o = 0; o < NH; o++)
            t[o] = (t[o] - m2) * rs2 * Wp[PLN2G + o] + Wp[PLN2B + o];

        // FFN2 -> scalar
        float yy = Wp[PF2B2];
        #pragma unroll
        for (int o = 0; o < NH; o++) {
            float a = Wp[PF2B1 + o];
            #pragma unroll
            for (int q = 0; q < 8; q++) {
                float4 w = lds4(Wp + PF2W1 + o * NH + 4 * q);
                a = fmaf(w.x, t[4*q+0], a); a = fmaf(w.y, t[4*q+1], a);
                a = fmaf(w.z, t[4*q+2], a); a = fmaf(w.w, t[4*q+3], a);
            }
            yy = fmaf(Wp[PF2W2 + o], fmaxf(a, 0.f), yy);
        }
        y = yy;
        seg = (l < L0_TOK) ? 0 : (l < L0_TOK + L1_TOK ? 1 : 2);
    }

    float s0 = (seg == 0 && active) ? y : 0.f;
    float s1 = (seg == 1 && active) ? y : 0.f;
    float sc = (seg == 2 && active) ? y : 0.f;
    #pragma unroll
    for (int off = 32; off > 0; off >>= 1) {
        s0 += __shfl_down(s0, off);
        s1 += __shfl_down(s1, off);
        sc += __shfl_down(sc, off);
    }
    const int wid = tid >> 6;
    if ((tid & 63) == 0) {
        red[wid * 3 + 0] = s0;
        red[wid * 3 + 1] = s1;
        red[wid * 3 + 2] = sc;
    }
    __syncthreads();
    if (tid == 0) {
        float a0 = 0.f, a1 = 0.f, a2 = 0.f;
        #pragma unroll
        for (int w = 0; w < 4; w++) {
            a0 += red[w * 3 + 0];
            a1 += red[w * 3 + 1];
            a2 += red[w * 3 + 2];
        }
        float* p = part + ((size_t)b * 3 + c) * 3;
        p[0] = a0; p[1] = a1; p[2] = a2;
    }
}

// =================== Kernel C: final reduction =============================
__global__ __launch_bounds__(256) void kernelC(
    const float* __restrict__ part, float* __restrict__ out, int B)
{
    int b = blockIdx.x * 256 + threadIdx.x;
    if (b >= B) return;
    const float* p = part + (size_t)b * 9;
    float a0 = p[0] + p[3] + p[6];
    float a1 = p[1] + p[4] + p[7];
    float a2 = p[2] + p[5] + p[8];
    out[b] = a0 / (float)L0_TOK + a1 / (float)L1_TOK + a2;
}

extern "C" void kernel_launch(void* const* d_in, const int* in_sizes, int n_in,
                              void* d_out, int out_size, void* d_ws, size_t ws_size,
                              hipStream_t stream)
{
    const float* x0   = (const float*)d_in[0];
    const float* x1   = (const float*)d_in[1];
    const float* pos0 = (const float*)d_in[2];
    const float* pos1 = (const float*)d_in[3];
    const float* xcT  = (const float*)d_in[4];
    const float* e0w1 = (const float*)d_in[5];
    const float* e0b1 = (const float*)d_in[6];
    const float* e0w2 = (const float*)d_in[7];
    const float* e0b2 = (const float*)d_in[8];
    const float* e1w1 = (const float*)d_in[9];
    const float* e1b1 = (const float*)d_in[10];
    const float* e1w2 = (const float*)d_in[11];
    const float* e1b2 = (const float*)d_in[12];
    const float* ecw1 = (const float*)d_in[13];
    const float* ecb1 = (const float*)d_in[14];
    const float* ecw2 = (const float*)d_in[15];
    const float* ecb2 = (const float*)d_in[16];
    const float* wq   = (const float*)d_in[17];
    const float* wk   = (const float*)d_in[18];
    const float* wv   = (const float*)d_in[19];
    const float* wo   = (const float*)d_in[20];
    const float* ln1g = (const float*)d_in[21];
    const float* ln1b = (const float*)d_in[22];
    const float* ln2g = (const float*)d_in[23];
    const float* ln2b = (const float*)d_in[24];
    const float* f1w1 = (const float*)d_in[25];
    const float* f1b1 = (const float*)d_in[26];
    const float* f1w2 = (const float*)d_in[27];
    const float* f1b2 = (const float*)d_in[28];
    const float* f2w1 = (const float*)d_in[29];
    const float* f2b1 = (const float*)d_in[30];
    const float* f2w2 = (const float*)d_in[31];
    const float* f2b2 = (const float*)d_in[32];
    float* out = (float*)d_out;

    const int B = in_sizes[0] / (L0_TOK * 8);

    float* wsf  = (float*)d_ws;
    float* wb   = wsf;                                  // B*1024 floats
    float* part = wsf + (size_t)B * (NH * NH);          // B*9 floats

    hipLaunchKernelGGL(kernelA, dim3(B), dim3(768), 0, stream,
                       x0, x1, pos0, pos1, xcT,
                       e0w1, e0b1, e0w2, e0b2, e1w1, e1b1, e1w2, e1b2,
                       ecw1, ecb1, ecw2, ecb2, wq, wk, wv, wo, wb);

    hipLaunchKernelGGL(kernelB, dim3(B, 3), dim3(256), 0, stream,
                       x0, x1, pos0, pos1, xcT,
                       e0w1, e0b1, e0w2, e0b2, e1w1, e1b1, e1w2, e1b2,
                       ecw1, ecb1, ecw2, ecb2, wb,
                       ln1g, ln1b, ln2g, ln2b,
                       f1w1, f1b1, f1w2, f1b2, f2w1, f2b1, f2w2, f2b2,
                       part);

    hipLaunchKernelGGL(kernelC, dim3((B + 255) / 256), dim3(256), 0, stream,
                       part, out, B);
}

// Round 7
// 640.900 us; speedup vs baseline: 1.5138x; 1.5138x over previous
//
#include <hip/hip_runtime.h>
#include <math.h>

#define L0T 365
#define L1T 366
#define LT  732      // 365 + 366 + 1
#define NTOK 736     // padded to 46 tiles of 16
#define NTILE 46
#define PI_F 3.14159265358979323846f

typedef short svec8 __attribute__((ext_vector_type(8)));   // 8 bf16 (4 VGPRs)
typedef float fvec4 __attribute__((ext_vector_type(4)));
typedef float fvec16 __attribute__((ext_vector_type(16)));

__device__ __forceinline__ unsigned short f2bf(float f) {
    unsigned u = __float_as_uint(f);
    u = (u + 0x7fffu + ((u >> 16) & 1u)) >> 16;
    return (unsigned short)u;
}
__device__ __forceinline__ float bf2f(unsigned short s) {
    return __uint_as_float(((unsigned)s) << 16);
}

// A-frag-friendly LDS layout for the full X/h buffer:
// AF(tok,feat) = ((tok>>4)*4 + (feat>>3))*128 + (tok&15)*8 + (feat&7)  [bf16 units]
// -> a-frag for tile t, lane l: contiguous 8 bf16 at (t*4 + (l>>4))*128 + (l&15)*8
#define AFT(lt, feat) ((((feat) >> 3) * 16 + (lt)) * 8 + ((feat) & 7))

__global__ __launch_bounds__(768, 3) void fused_kernel(
    const float* __restrict__ x0,  const float* __restrict__ x1,
    const float* __restrict__ pos0,const float* __restrict__ pos1,
    const float* __restrict__ xcT,
    const float* __restrict__ e0w1,const float* __restrict__ e0b1,
    const float* __restrict__ e0w2,const float* __restrict__ e0b2,
    const float* __restrict__ e1w1,const float* __restrict__ e1b1,
    const float* __restrict__ e1w2,const float* __restrict__ e1b2,
    const float* __restrict__ ecw1,const float* __restrict__ ecb1,
    const float* __restrict__ ecw2,const float* __restrict__ ecb2,
    const float* __restrict__ wq,  const float* __restrict__ wk,
    const float* __restrict__ wv,  const float* __restrict__ wo,
    const float* __restrict__ ln1g,const float* __restrict__ ln1b,
    const float* __restrict__ ln2g,const float* __restrict__ ln2b,
    const float* __restrict__ f1w1,const float* __restrict__ f1b1,
    const float* __restrict__ f1w2,const float* __restrict__ f1b2,
    const float* __restrict__ f2w1,const float* __restrict__ f2b1,
    const float* __restrict__ f2w2,const float* __restrict__ f2b2,
    float* __restrict__ out)
{
    const int b    = blockIdx.x;
    const int tid  = threadIdx.x;
    const int wvid = tid >> 6;   // NOTE: must not shadow param 'wv'
    const int ln   = tid & 63;
    const int r    = ln & 15;    // 16x16 MFMA: A-row / C-col index
    const int quad = ln >> 4;    // 16x16 MFMA: k-slice / C-row group

    __shared__ unsigned short HX[NTOK * 32] __attribute__((aligned(16))); // 47104 B
    __shared__ char U[16384] __attribute__((aligned(16)));                // phase-aliased
    __shared__ float red[36];

    float* Uf = (float*)U;
    // Phase 1 aliases: layer1 weights (f32) + layer2 weights (bf16)
    float* L1Wf = Uf;                                       // 896 floats @0
    unsigned short* W2u = (unsigned short*)(U + 3584);      // 2048 u16
    // Phase G/C aliases
    float* Cmf = Uf;                                        // 1024 f @0
    float* T1f = (float*)(U + 4096);
    float* T2f = (float*)(U + 8192);
    unsigned short* Wbb = (unsigned short*)(U + 12288);     // 1024 u16 (Wb+I, bf16)
    // Phase P alias: per-wave 1 KB restage buffers @0..12288
    unsigned short* bufT = (unsigned short*)U;

    // ---------------- stage layer1 (f32) + layer2 (bf16) weights ----------------
    for (int i = tid; i < 896; i += 768) {
        float v;
        if      (i < 256) v = e0w1[i];          // [0,256)   e0w1 32x8
        else if (i < 288) v = e0b1[i - 256];    // [256,288) e0b1
        else if (i < 320) v = e0b2[i - 288];    // [288,320) e0b2
        else if (i < 832) v = e1w1[i - 320];    // [320,832) e1w1 32x16
        else if (i < 864) v = e1b1[i - 832];    // [832,864) e1b1
        else              v = e1b2[i - 864];    // [864,896) e1b2
        L1Wf[i] = v;
    }
    for (int i = tid; i < 2048; i += 768)
        W2u[i] = f2bf(i < 1024 ? e0w2[i] : e1w2[i - 1024]);
    __syncthreads();

    // ---------------- layer1: one token per thread -> h (bf16, A-frag layout) ---
    if (tid < NTOK) {
        const int tok = tid;
        unsigned short hh[32];
        if (tok < L0T) {
            const float4* px = (const float4*)(x0 + ((size_t)b * L0T + tok) * 8);
            float4 i0 = px[0], i1 = px[1];
            #pragma unroll
            for (int o = 0; o < 32; o++) {
                const float* wr = L1Wf + o * 8;
                float a = L1Wf[256 + o];
                a = fmaf(wr[0], i0.x, a); a = fmaf(wr[1], i0.y, a);
                a = fmaf(wr[2], i0.z, a); a = fmaf(wr[3], i0.w, a);
                a = fmaf(wr[4], i1.x, a); a = fmaf(wr[5], i1.y, a);
                a = fmaf(wr[6], i1.z, a); a = fmaf(wr[7], i1.w, a);
                hh[o] = f2bf(fmaxf(a, 0.f));
            }
        } else if (tok < LT - 1) {
            const int tt = tok - L0T;
            const float4* px = (const float4*)(x1 + ((size_t)b * L1T + tt) * 16);
            float4 i0 = px[0], i1 = px[1], i2 = px[2], i3 = px[3];
            float in[16] = {i0.x,i0.y,i0.z,i0.w, i1.x,i1.y,i1.z,i1.w,
                            i2.x,i2.y,i2.z,i2.w, i3.x,i3.y,i3.z,i3.w};
            #pragma unroll
            for (int o = 0; o < 32; o++) {
                const float* wr = L1Wf + 320 + o * 16;
                float a = L1Wf[832 + o];
                #pragma unroll
                for (int i = 0; i < 16; i++) a = fmaf(wr[i], in[i], a);
                hh[o] = f2bf(fmaxf(a, 0.f));
            }
        } else {
            // tok 731 (ec, handled later) and pads 732-735: zero h
            #pragma unroll
            for (int o = 0; o < 32; o++) hh[o] = 0;
        }
        #pragma unroll
        for (int q = 0; q < 4; q++) {
            svec8 s;
            #pragma unroll
            for (int j = 0; j < 8; j++) s[j] = (short)hh[q * 8 + j];
            *(svec8*)&HX[((tok >> 4) * 4 + q) * 128 + (tok & 15) * 8] = s;
        }
    }
    __syncthreads();

    // ---------------- layer2: MFMA per tile, in-place h -> X (+bias+posenc) -----
    // 47 passes: p<23 -> e0 weights, tile p (valid tok<365);
    //            p>=23 -> e1 weights, tile p-1 (valid 365<=tok<=730).
    // In-place is race-free: D row m depends only on A row m; each pass only
    // consumes/writes rows valid for it.
    for (int p = wvid; p < 47; p += 12) {
        const int ef = (p >= 23) ? 1 : 0;
        const int t  = ef ? (p - 1) : p;
        svec8 af = *(const svec8*)&HX[(t * 4 + quad) * 128 + r * 8];
        svec8 b0 = *(const svec8*)&W2u[ef * 1024 + r * 32 + quad * 8];
        svec8 b1 = *(const svec8*)&W2u[ef * 1024 + (r + 16) * 32 + quad * 8];
        fvec4 d0 = {0.f,0.f,0.f,0.f}, d1 = {0.f,0.f,0.f,0.f};
        d0 = __builtin_amdgcn_mfma_f32_16x16x32_bf16(af, b0, d0, 0, 0, 0);
        d1 = __builtin_amdgcn_mfma_f32_16x16x32_bf16(af, b1, d1, 0, 0, 0);
        #pragma unroll
        for (int rg = 0; rg < 4; rg++) {
            const int lt  = quad * 4 + rg;
            const int tok = t * 16 + lt;
            const bool valid = ef ? (tok >= L0T && tok <= LT - 2) : (tok < L0T);
            if (valid) {
                float pv = ef ? pos1[(size_t)b * L1T + (tok - L0T)]
                              : pos0[(size_t)b * L0T + tok];
                const int f0 = r, f1i = r + 16;
                float a0 = pv * (PI_F / (float)((f0 >> 1) + 1));
                float a1 = pv * (PI_F / (float)((f1i >> 1) + 1));
                float p0 = (f0 & 1)  ? __cosf(a0) : __sinf(a0);
                float p1 = (f1i & 1) ? __cosf(a1) : __sinf(a1);
                float v0 = d0[rg] + L1Wf[(ef ? 864 : 288) + f0] + p0;
                float v1 = d1[rg] + L1Wf[(ef ? 864 : 288) + f1i] + p1;
                HX[(t * 4 + (f0 >> 3)) * 128 + lt * 8 + (f0 & 7)]  = f2bf(v0);
                HX[(t * 4 + (f1i >> 3)) * 128 + lt * 8 + (f1i & 7)] = f2bf(v1);
            }
        }
    }
    // ec token (731): full VALU path, single lane
    if (tid == LT - 1) {
        float in[32], h[32];
        #pragma unroll
        for (int i = 0; i < 32; i++) in[i] = xcT[(size_t)b * 32 + i];
        #pragma unroll
        for (int o = 0; o < 32; o++) {
            float a = ecb1[o];
            #pragma unroll
            for (int i = 0; i < 32; i++) a = fmaf(ecw1[o * 32 + i], in[i], a);
            h[o] = fmaxf(a, 0.f);
        }
        #pragma unroll
        for (int q = 0; q < 4; q++) {
            svec8 s;
            #pragma unroll
            for (int j = 0; j < 8; j++) {
                int o = q * 8 + j;
                float a = ecb2[o];
                #pragma unroll
                for (int jj = 0; jj < 32; jj++) a = fmaf(ecw2[o * 32 + jj], h[jj], a);
                s[j] = (short)f2bf(a);
            }
            *(svec8*)&HX[(45 * 4 + q) * 128 + 11 * 8] = s;   // tok 731 = tile45,lt=11
        }
    }
    __syncthreads();

    // ---------------- Gram: C = X^T X via mfma_32x32x16 (a-frag == b-frag) ------
    for (int i = tid; i < 1024; i += 768) Cmf[i] = 0.f;
    __syncthreads();
    {
        const int feat = ln & 31;
        const int half = ln >> 5;
        fvec16 dG;
        #pragma unroll
        for (int i = 0; i < 16; i++) dG[i] = 0.f;
        for (int c = wvid; c < NTILE; c += 12) {
            svec8 af;
            #pragma unroll
            for (int j = 0; j < 8; j++) {
                int tok = c * 16 + half * 8 + j;
                af[j] = (short)HX[((tok >> 4) * 4 + (feat >> 3)) * 128
                                  + (tok & 15) * 8 + (feat & 7)];
            }
            dG = __builtin_amdgcn_mfma_f32_32x32x16_bf16(af, af, dG, 0, 0, 0);
        }
        #pragma unroll
        for (int rg = 0; rg < 16; rg++) {
            int row = (rg & 3) + 8 * (rg >> 2) + 4 * half;
            atomicAdd(&Cmf[row * 32 + feat], dG[rg]);
        }
    }
    __syncthreads();

    // ---------------- attention collapse (verified round-5 code) ----------------
    for (int idx = tid; idx < 1024; idx += 768) {
        int i = idx >> 5, g = idx & 31;
        float a = 0.f;
        #pragma unroll
        for (int j = 0; j < 32; j++) a = fmaf(Cmf[i * 32 + j], wk[g * 32 + j], a);
        T1f[i * 32 + g] = a;
    }
    __syncthreads();
    const float rsL = rsqrtf((float)LT);
    for (int idx = tid; idx < 1024; idx += 768) {
        int h = idx >> 5, g = idx & 31;
        float a = 0.f;
        #pragma unroll
        for (int i = 0; i < 32; i++) a = fmaf(wq[h * 32 + i], T1f[i * 32 + g], a);
        T2f[h * 32 + g] = a * rsL;
    }
    __syncthreads();
    if (tid < 32) {
        float mx = -1e30f;
        #pragma unroll
        for (int g = 0; g < 32; g++) mx = fmaxf(mx, T2f[tid * 32 + g]);
        float s = 0.f;
        #pragma unroll
        for (int g = 0; g < 32; g++) {
            float e = __expf(T2f[tid * 32 + g] - mx);
            T2f[tid * 32 + g] = e; s += e;
        }
        float inv = 1.f / s;
        #pragma unroll
        for (int g = 0; g < 32; g++) T2f[tid * 32 + g] *= inv;
    }
    __syncthreads();
    for (int idx = tid; idx < 1024; idx += 768) {
        int h = idx >> 5, j = idx & 31;
        float a = 0.f;
        #pragma unroll
        for (int g = 0; g < 32; g++) a = fmaf(T2f[h * 32 + g], wv[g * 32 + j], a);
        T1f[h * 32 + j] = a;
    }
    __syncthreads();
    for (int idx = tid; idx < 1024; idx += 768) {
        int o = idx >> 5, j = idx & 31;
        float a = 0.f;
        #pragma unroll
        for (int h = 0; h < 32; h++) a = fmaf(wo[o * 32 + h], T1f[h * 32 + j], a);
        Wbb[o * 32 + j] = f2bf(a + (o == j ? 1.f : 0.f));   // (Wb + I) bf16
    }
    __syncthreads();

    // ---------------- pipeline: MFMA per 16-token tile --------------------------
    // Weight B-frags live in registers (no per-token weight traffic).
    svec8 bwb0 = *(const svec8*)&Wbb[r * 32 + quad * 8];
    svec8 bwb1 = *(const svec8*)&Wbb[(r + 16) * 32 + quad * 8];
    svec8 bfa0, bfa1, bfb0, bfb1, bfc0, bfc1;
    #pragma unroll
    for (int j = 0; j < 8; j++) {
        int k = quad * 8 + j;
        bfa0[j] = (short)f2bf(f1w1[r * 32 + k]);
        bfa1[j] = (short)f2bf(f1w1[(r + 16) * 32 + k]);
        bfb0[j] = (short)f2bf(f1w2[r * 32 + k]);
        bfb1[j] = (short)f2bf(f1w2[(r + 16) * 32 + k]);
        bfc0[j] = (short)f2bf(f2w1[r * 32 + k]);
        bfc1[j] = (short)f2bf(f2w1[(r + 16) * 32 + k]);
    }
    const float g1a = ln1g[r], g1b = ln1g[r + 16], q1a = ln1b[r], q1b = ln1b[r + 16];
    const float g2a = ln2g[r], g2b = ln2g[r + 16], q2a = ln2b[r], q2b = ln2b[r + 16];
    const float c1a = f1b1[r], c1b = f1b1[r + 16];
    const float c2a = f1b2[r], c2b = f1b2[r + 16];
    const float c3a = f2b1[r], c3b = f2b1[r + 16];
    const float wya = f2w2[r], wyb = f2w2[r + 16];
    const float ybias = f2b2[0];

    unsigned short* bt = bufT + wvid * 512;   // per-wave private restage buffer
    float s0 = 0.f, s1 = 0.f, s2 = 0.f;

    for (int t = wvid; t < NTILE; t += 12) {
        svec8 xf = *(const svec8*)&HX[(t * 4 + quad) * 128 + r * 8];
        fvec4 d0 = {0.f,0.f,0.f,0.f}, d1 = {0.f,0.f,0.f,0.f};
        d0 = __builtin_amdgcn_mfma_f32_16x16x32_bf16(xf, bwb0, d0, 0, 0, 0);
        d1 = __builtin_amdgcn_mfma_f32_16x16x32_bf16(xf, bwb1, d1, 0, 0, 0);
        // LN1 (row = token in C-layout; 16-lane shfl_xor reduce over features)
        float t0[4], t1[4];
        #pragma unroll
        for (int rg = 0; rg < 4; rg++) {
            float s = d0[rg] + d1[rg];
            s += __shfl_xor(s, 1); s += __shfl_xor(s, 2);
            s += __shfl_xor(s, 4); s += __shfl_xor(s, 8);
            float mean = s * (1.f / 32.f);
            float ea = d0[rg] - mean, eb = d1[rg] - mean;
            float vva = ea * ea + eb * eb;
            vva += __shfl_xor(vva, 1); vva += __shfl_xor(vva, 2);
            vva += __shfl_xor(vva, 4); vva += __shfl_xor(vva, 8);
            float rsd = rsqrtf(vva * (1.f / 32.f) + 1e-5f);
            t0[rg] = ea * rsd * g1a + q1a;
            t1[rg] = eb * rsd * g1b + q1b;
        }
        #pragma unroll
        for (int rg = 0; rg < 4; rg++) {
            int lt = quad * 4 + rg;
            bt[AFT(lt, r)]      = f2bf(t0[rg]);
            bt[AFT(lt, r + 16)] = f2bf(t1[rg]);
        }
        __asm__ __volatile__("" ::: "memory");
        svec8 tf = *(const svec8*)&bt[(quad * 16 + r) * 8];
        fvec4 u0 = {0.f,0.f,0.f,0.f}, u1 = {0.f,0.f,0.f,0.f};
        u0 = __builtin_amdgcn_mfma_f32_16x16x32_bf16(tf, bfa0, u0, 0, 0, 0);
        u1 = __builtin_amdgcn_mfma_f32_16x16x32_bf16(tf, bfa1, u1, 0, 0, 0);
        __asm__ __volatile__("" ::: "memory");
        #pragma unroll
        for (int rg = 0; rg < 4; rg++) {
            int lt = quad * 4 + rg;
            bt[AFT(lt, r)]      = f2bf(fmaxf(u0[rg] + c1a, 0.f));
            bt[AFT(lt, r + 16)] = f2bf(fmaxf(u1[rg] + c1b, 0.f));
        }
        __asm__ __volatile__("" ::: "memory");
        svec8 uf = *(const svec8*)&bt[(quad * 16 + r) * 8];
        fvec4 w0 = {0.f,0.f,0.f,0.f}, w1 = {0.f,0.f,0.f,0.f};
        w0 = __builtin_amdgcn_mfma_f32_16x16x32_bf16(uf, bfb0, w0, 0, 0, 0);
        w1 = __builtin_amdgcn_mfma_f32_16x16x32_bf16(uf, bfb1, w1, 0, 0, 0);
        // + f1b2 + residual x, then LN2
        #pragma unroll
        for (int rg = 0; rg < 4; rg++) {
            int lt = quad * 4 + rg;
            float xr0 = bf2f(HX[(t * 4 + (r >> 3)) * 128 + lt * 8 + (r & 7)]);
            float xr1 = bf2f(HX[(t * 4 + 2 + (r >> 3)) * 128 + lt * 8 + (r & 7)]);
            float va = w0[rg] + c2a + xr0;
            float vb = w1[rg] + c2b + xr1;
            float s = va + vb;
            s += __shfl_xor(s, 1); s += __shfl_xor(s, 2);
            s += __shfl_xor(s, 4); s += __shfl_xor(s, 8);
            float mean = s * (1.f / 32.f);
            float ea = va - mean, eb = vb - mean;
            float vva = ea * ea + eb * eb;
            vva += __shfl_xor(vva, 1); vva += __shfl_xor(vva, 2);
            vva += __shfl_xor(vva, 4); vva += __shfl_xor(vva, 8);
            float rsd = rsqrtf(vva * (1.f / 32.f) + 1e-5f);
            t0[rg] = ea * rsd * g2a + q2a;
            t1[rg] = eb * rsd * g2b + q2b;
        }
        __asm__ __volatile__("" ::: "memory");
        #pragma unroll
        for (int rg = 0; rg < 4; rg++) {
            int lt = quad * 4 + rg;
            bt[AFT(lt, r)]      = f2bf(t0[rg]);
            bt[AFT(lt, r + 16)] = f2bf(t1[rg]);
        }
        __asm__ __volatile__("" ::: "memory");
        svec8 t2f = *(const svec8*)&bt[(quad * 16 + r) * 8];
        fvec4 e0d = {0.f,0.f,0.f,0.f}, e1d = {0.f,0.f,0.f,0.f};
        e0d = __builtin_amdgcn_mfma_f32_16x16x32_bf16(t2f, bfc0, e0d, 0, 0, 0);
        e1d = __builtin_amdgcn_mfma_f32_16x16x32_bf16(t2f, bfc1, e1d, 0, 0, 0);
        #pragma unroll
        for (int rg = 0; rg < 4; rg++) {
            float py = wya * fmaxf(e0d[rg] + c3a, 0.f)
                     + wyb * fmaxf(e1d[rg] + c3b, 0.f);
            py += __shfl_xor(py, 1); py += __shfl_xor(py, 2);
            py += __shfl_xor(py, 4); py += __shfl_xor(py, 8);
            if (r == 0) {                       // one leader per 16-lane group
                int tok = t * 16 + quad * 4 + rg;
                float yv = py + ybias;
                if (tok < L0T)          s0 += yv;
                else if (tok < LT - 1)  s1 += yv;
                else if (tok == LT - 1) s2 += yv;
                // tok 732-735: padding, dropped
            }
        }
    }

    // wave totals (non-leader lanes hold 0) then block total
    s0 += __shfl_xor(s0, 16); s0 += __shfl_xor(s0, 32);
    s1 += __shfl_xor(s1, 16); s1 += __shfl_xor(s1, 32);
    s2 += __shfl_xor(s2, 16); s2 += __shfl_xor(s2, 32);
    if (ln == 0) {
        red[wvid * 3] = s0; red[wvid * 3 + 1] = s1; red[wvid * 3 + 2] = s2;
    }
    __syncthreads();
    if (tid == 0) {
        float a0 = 0.f, a1 = 0.f, a2 = 0.f;
        #pragma unroll
        for (int w = 0; w < 12; w++) {
            a0 += red[w * 3]; a1 += red[w * 3 + 1]; a2 += red[w * 3 + 2];
        }
        out[b] = a0 / (float)L0T + a1 / (float)L1T + a2;
    }
}

extern "C" void kernel_launch(void* const* d_in, const int* in_sizes, int n_in,
                              void* d_out, int out_size, void* d_ws, size_t ws_size,
                              hipStream_t stream)
{
    const float* x0   = (const float*)d_in[0];
    const float* x1   = (const float*)d_in[1];
    const float* pos0 = (const float*)d_in[2];
    const float* pos1 = (const float*)d_in[3];
    const float* xcT  = (const float*)d_in[4];
    const float* e0w1 = (const float*)d_in[5];
    const float* e0b1 = (const float*)d_in[6];
    const float* e0w2 = (const float*)d_in[7];
    const float* e0b2 = (const float*)d_in[8];
    const float* e1w1 = (const float*)d_in[9];
    const float* e1b1 = (const float*)d_in[10];
    const float* e1w2 = (const float*)d_in[11];
    const float* e1b2 = (const float*)d_in[12];
    const float* ecw1 = (const float*)d_in[13];
    const float* ecb1 = (const float*)d_in[14];
    const float* ecw2 = (const float*)d_in[15];
    const float* ecb2 = (const float*)d_in[16];
    const float* wq   = (const float*)d_in[17];
    const float* wk   = (const float*)d_in[18];
    const float* wv   = (const float*)d_in[19];
    const float* wo   = (const float*)d_in[20];
    const float* ln1g = (const float*)d_in[21];
    const float* ln1b = (const float*)d_in[22];
    const float* ln2g = (const float*)d_in[23];
    const float* ln2b = (const float*)d_in[24];
    const float* f1w1 = (const float*)d_in[25];
    const float* f1b1 = (const float*)d_in[26];
    const float* f1w2 = (const float*)d_in[27];
    const float* f1b2 = (const float*)d_in[28];
    const float* f2w1 = (const float*)d_in[29];
    const float* f2b1 = (const float*)d_in[30];
    const float* f2w2 = (const float*)d_in[31];
    const float* f2b2 = (const float*)d_in[32];
    float* out = (float*)d_out;

    const int B = in_sizes[0] / (L0T * 8);

    hipLaunchKernelGGL(fused_kernel, dim3(B), dim3(768), 0, stream,
                       x0, x1, pos0, pos1, xcT,
                       e0w1, e0b1, e0w2, e0b2, e1w1, e1b1, e1w2, e1b2,
                       ecw1, ecb1, ecw2, ecb2, wq, wk, wv, wo,
                       ln1g, ln1b, ln2g, ln2b,
                       f1w1, f1b1, f1w2, f1b2, f2w1, f2b1, f2w2, f2b2,
                       out);
}

// Round 8
// 449.139 us; speedup vs baseline: 2.1601x; 1.4270x over previous
//
#include <hip/hip_runtime.h>
#include <math.h>

#define L0T 365
#define L1T 366
#define LT  732
#define NTILE 46
#define NW   8
#define NTHR 512
#define PI_F 3.14159265358979323846f

typedef short svec8 __attribute__((ext_vector_type(8)));   // 8 bf16
typedef float fvec4 __attribute__((ext_vector_type(4)));
typedef float fvec16 __attribute__((ext_vector_type(16)));

__device__ __forceinline__ unsigned short f2bf(float f) {
    unsigned u = __float_as_uint(f);
    u = (u + 0x7fffu + ((u >> 16) & 1u)) >> 16;
    return (unsigned short)u;
}
__device__ __forceinline__ float bf2f(unsigned short s) {
    return __uint_as_float(((unsigned)s) << 16);
}
__device__ __forceinline__ unsigned pk2(float a, float b) {
    return (unsigned)f2bf(a) | ((unsigned)f2bf(b) << 16);
}
__device__ __forceinline__ float pget(const unsigned* p, int j) {
    unsigned u = p[j >> 1];
    return bf2f((unsigned short)((j & 1) ? (u >> 16) : (u & 0xffff)));
}

// XT: feature-major bf16 X^T [32 feats][92 token-blocks of 8], row stride 93
// blocks, block index XOR-swizzled by the feature octet for bank spread.
// addr(feat, tok) = (feat*93 + ((tok>>3) ^ ((feat>>3)&3)))*8 + (tok&7)
#define XTBLK(feat, tokblk) (((feat) * 93 + ((tokblk) ^ (((feat) >> 3) & 3))) * 8)

__global__ __launch_bounds__(NTHR, 4) void fused_kernel(
    const float* __restrict__ x0,  const float* __restrict__ x1,
    const float* __restrict__ pos0,const float* __restrict__ pos1,
    const float* __restrict__ xcT,
    const float* __restrict__ e0w1,const float* __restrict__ e0b1,
    const float* __restrict__ e0w2,const float* __restrict__ e0b2,
    const float* __restrict__ e1w1,const float* __restrict__ e1b1,
    const float* __restrict__ e1w2,const float* __restrict__ e1b2,
    const float* __restrict__ ecw1,const float* __restrict__ ecb1,
    const float* __restrict__ ecw2,const float* __restrict__ ecb2,
    const float* __restrict__ wq,  const float* __restrict__ wk,
    const float* __restrict__ wv,  const float* __restrict__ wo,
    const float* __restrict__ ln1g,const float* __restrict__ ln1b,
    const float* __restrict__ ln2g,const float* __restrict__ ln2b,
    const float* __restrict__ f1w1,const float* __restrict__ f1b1,
    const float* __restrict__ f1w2,const float* __restrict__ f1b2,
    const float* __restrict__ f2w1,const float* __restrict__ f2b1,
    const float* __restrict__ f2w2,const float* __restrict__ f2b2,
    float* __restrict__ out)
{
    const int b   = blockIdx.x;
    const int tid = threadIdx.x;
    const int w   = tid >> 6;          // wave 0..7
    const int ln  = tid & 63;
    const int tk  = ln & 15;           // token-in-tile (MFMA column n / A-row slot)
    const int Q   = ln >> 4;           // k-octet / C-row quad
    // A-frag logical weight-row for the permutation trick:
    // D-slot s=quad*4+rg  <- logical feat quad*8+rg (frag0) / +4 (frag1)
    const int Lr0 = ((tk >> 2) * 8) + (tk & 3);
    const int Lr1 = Lr0 + 4;

    __shared__ unsigned short XT[32 * 93 * 8] __attribute__((aligned(16))); // 47616 B
    __shared__ float Cm[1024];
    __shared__ float T1f[1024];
    __shared__ float T2f[1024];
    __shared__ unsigned short Wbb[1024] __attribute__((aligned(16)));
    __shared__ float red[NW * 3];

    // zero Gram accumulator + XT pad columns (tokens 732..735)
    for (int i = tid; i < 1024; i += NTHR) Cm[i] = 0.f;
    if (tid < 128) {
        int feat = tid >> 2, off = 4 + (tid & 3);
        XT[XTBLK(feat, 91) + off] = 0;
    }

    // posenc angular constants for this lane's feats Q*8+j
    float pw[8];
    #pragma unroll
    for (int j = 0; j < 8; j++) pw[j] = PI_F / (float)(Q * 4 + (j >> 1) + 1);

    const fvec4 zc = {0.f, 0.f, 0.f, 0.f};

    // =================== EMBED: 3 weight-set sweeps =====================
    // ---- e0 (tiles 0..22, valid tok < 365) ----
    {
        svec8 w1f0, w1f1, w2f0, w2f1;
        float hb8[8], xb8[8];
        #pragma unroll
        for (int j = 0; j < 8; j++) {
            w1f0[j] = (Q == 0) ? (short)f2bf(e0w1[Lr0 * 8 + j]) : (short)0;
            w1f1[j] = (Q == 0) ? (short)f2bf(e0w1[Lr1 * 8 + j]) : (short)0;
            w2f0[j] = (short)f2bf(e0w2[Lr0 * 32 + Q * 8 + j]);
            w2f1[j] = (short)f2bf(e0w2[Lr1 * 32 + Q * 8 + j]);
            hb8[j]  = e0b1[Q * 8 + j];
            xb8[j]  = e0b2[Q * 8 + j];
        }
        for (int t = w; t <= 22; t += NW) {
            const int tok = t * 16 + tk;
            const bool valid = (tok < L0T);
            svec8 bx;
            #pragma unroll
            for (int j = 0; j < 8; j++) bx[j] = 0;
            if (Q == 0 && valid) {
                const float4* px = (const float4*)(x0 + ((size_t)b * L0T + tok) * 8);
                float4 a = px[0], c = px[1];
                bx[0]=(short)f2bf(a.x); bx[1]=(short)f2bf(a.y);
                bx[2]=(short)f2bf(a.z); bx[3]=(short)f2bf(a.w);
                bx[4]=(short)f2bf(c.x); bx[5]=(short)f2bf(c.y);
                bx[6]=(short)f2bf(c.z); bx[7]=(short)f2bf(c.w);
            }
            float pv = valid ? pos0[(size_t)b * L0T + tok] : 0.f;
            fvec4 d0 = __builtin_amdgcn_mfma_f32_16x16x32_bf16(w1f0, bx, zc, 0,0,0);
            fvec4 d1 = __builtin_amdgcn_mfma_f32_16x16x32_bf16(w1f1, bx, zc, 0,0,0);
            svec8 hf;
            #pragma unroll
            for (int j = 0; j < 4; j++) {
                hf[j]   = (short)f2bf(fmaxf(d0[j] + hb8[j], 0.f));
                hf[4+j] = (short)f2bf(fmaxf(d1[j] + hb8[4+j], 0.f));
            }
            fvec4 g0 = __builtin_amdgcn_mfma_f32_16x16x32_bf16(w2f0, hf, zc, 0,0,0);
            fvec4 g1 = __builtin_amdgcn_mfma_f32_16x16x32_bf16(w2f1, hf, zc, 0,0,0);
            if (valid) {
                const int base = XTBLK(0, (t * 2 + (tk >> 3))) ; // feat 0 base (Q=0 swizzle uses ^0)
                const int tb = (t * 2 + (tk >> 3)) ^ Q;
                #pragma unroll
                for (int j = 0; j < 8; j++) {
                    float xv = (j < 4 ? g0[j] : g1[j - 4]) + xb8[j];
                    float ang = pv * pw[j];
                    xv += (j & 1) ? __cosf(ang) : __sinf(ang);
                    XT[((Q * 8 + j) * 93 + tb) * 8 + (tk & 7)] = f2bf(xv);
                }
                (void)base;
            }
        }
    }
    // ---- e1 (tiles 22..45, valid 365 <= tok <= 730) ----
    {
        svec8 w1f0, w1f1, w2f0, w2f1;
        float hb8[8], xb8[8];
        #pragma unroll
        for (int j = 0; j < 8; j++) {
            w1f0[j] = (Q < 2) ? (short)f2bf(e1w1[Lr0 * 16 + Q * 8 + j]) : (short)0;
            w1f1[j] = (Q < 2) ? (short)f2bf(e1w1[Lr1 * 16 + Q * 8 + j]) : (short)0;
            w2f0[j] = (short)f2bf(e1w2[Lr0 * 32 + Q * 8 + j]);
            w2f1[j] = (short)f2bf(e1w2[Lr1 * 32 + Q * 8 + j]);
            hb8[j]  = e1b1[Q * 8 + j];
            xb8[j]  = e1b2[Q * 8 + j];
        }
        for (int t = 22 + w; t <= 45; t += NW) {
            const int tok = t * 16 + tk;
            const bool valid = (tok >= L0T && tok <= LT - 2);
            svec8 bx;
            #pragma unroll
            for (int j = 0; j < 8; j++) bx[j] = 0;
            if (Q < 2 && valid) {
                const float4* px = (const float4*)(x1 + ((size_t)b * L1T + (tok - L0T)) * 16 + Q * 8);
                float4 a = px[0], c = px[1];
                bx[0]=(short)f2bf(a.x); bx[1]=(short)f2bf(a.y);
                bx[2]=(short)f2bf(a.z); bx[3]=(short)f2bf(a.w);
                bx[4]=(short)f2bf(c.x); bx[5]=(short)f2bf(c.y);
                bx[6]=(short)f2bf(c.z); bx[7]=(short)f2bf(c.w);
            }
            float pv = valid ? pos1[(size_t)b * L1T + (tok - L0T)] : 0.f;
            fvec4 d0 = __builtin_amdgcn_mfma_f32_16x16x32_bf16(w1f0, bx, zc, 0,0,0);
            fvec4 d1 = __builtin_amdgcn_mfma_f32_16x16x32_bf16(w1f1, bx, zc, 0,0,0);
            svec8 hf;
            #pragma unroll
            for (int j = 0; j < 4; j++) {
                hf[j]   = (short)f2bf(fmaxf(d0[j] + hb8[j], 0.f));
                hf[4+j] = (short)f2bf(fmaxf(d1[j] + hb8[4+j], 0.f));
            }
            fvec4 g0 = __builtin_amdgcn_mfma_f32_16x16x32_bf16(w2f0, hf, zc, 0,0,0);
            fvec4 g1 = __builtin_amdgcn_mfma_f32_16x16x32_bf16(w2f1, hf, zc, 0,0,0);
            if (valid) {
                const int tb = (t * 2 + (tk >> 3)) ^ Q;
                #pragma unroll
                for (int j = 0; j < 8; j++) {
                    float xv = (j < 4 ? g0[j] : g1[j - 4]) + xb8[j];
                    float ang = pv * pw[j];
                    xv += (j & 1) ? __cosf(ang) : __sinf(ang);
                    XT[((Q * 8 + j) * 93 + tb) * 8 + (tk & 7)] = f2bf(xv);
                }
            }
        }
    }
    // ---- ec (tile 45, valid tok == 731 i.e. tk == 11; no posenc) ----
    if (w == 7) {
        svec8 w1f0, w1f1, w2f0, w2f1;
        float hb8[8], xb8[8];
        #pragma unroll
        for (int j = 0; j < 8; j++) {
            w1f0[j] = (short)f2bf(ecw1[Lr0 * 32 + Q * 8 + j]);
            w1f1[j] = (short)f2bf(ecw1[Lr1 * 32 + Q * 8 + j]);
            w2f0[j] = (short)f2bf(ecw2[Lr0 * 32 + Q * 8 + j]);
            w2f1[j] = (short)f2bf(ecw2[Lr1 * 32 + Q * 8 + j]);
            hb8[j]  = ecb1[Q * 8 + j];
            xb8[j]  = ecb2[Q * 8 + j];
        }
        svec8 bx;
        const float4* px = (const float4*)(xcT + (size_t)b * 32 + Q * 8);
        {
            float4 a = px[0], c = px[1];
            bx[0]=(short)f2bf(a.x); bx[1]=(short)f2bf(a.y);
            bx[2]=(short)f2bf(a.z); bx[3]=(short)f2bf(a.w);
            bx[4]=(short)f2bf(c.x); bx[5]=(short)f2bf(c.y);
            bx[6]=(short)f2bf(c.z); bx[7]=(short)f2bf(c.w);
        }
        fvec4 d0 = __builtin_amdgcn_mfma_f32_16x16x32_bf16(w1f0, bx, zc, 0,0,0);
        fvec4 d1 = __builtin_amdgcn_mfma_f32_16x16x32_bf16(w1f1, bx, zc, 0,0,0);
        svec8 hf;
        #pragma unroll
        for (int j = 0; j < 4; j++) {
            hf[j]   = (short)f2bf(fmaxf(d0[j] + hb8[j], 0.f));
            hf[4+j] = (short)f2bf(fmaxf(d1[j] + hb8[4+j], 0.f));
        }
        fvec4 g0 = __builtin_amdgcn_mfma_f32_16x16x32_bf16(w2f0, hf, zc, 0,0,0);
        fvec4 g1 = __builtin_amdgcn_mfma_f32_16x16x32_bf16(w2f1, hf, zc, 0,0,0);
        if (tk == 11) {                          // token 731 column only
            const int tb = (45 * 2 + (tk >> 3)) ^ Q;
            #pragma unroll
            for (int j = 0; j < 8; j++) {
                float xv = (j < 4 ? g0[j] : g1[j - 4]) + xb8[j];
                XT[((Q * 8 + j) * 93 + tb) * 8 + (tk & 7)] = f2bf(xv);
            }
        }
    }
    __syncthreads();

    // =================== GRAM: C = X^T X via mfma_32x32x16 ==============
    {
        const int feat = ln & 31, half = ln >> 5;
        const int qf = (feat >> 3) & 3;
        fvec16 dG;
        #pragma unroll
        for (int i = 0; i < 16; i++) dG[i] = 0.f;
        for (int c = w; c < NTILE; c += NW) {
            svec8 af = *(const svec8*)&XT[(feat * 93 + ((c * 2 + half) ^ qf)) * 8];
            dG = __builtin_amdgcn_mfma_f32_32x32x16_bf16(af, af, dG, 0, 0, 0);
        }
        #pragma unroll
        for (int rg = 0; rg < 16; rg++) {
            int row = (rg & 3) + 8 * (rg >> 2) + 4 * half;
            atomicAdd(&Cm[row * 32 + feat], dG[rg]);
        }
    }
    __syncthreads();

    // =================== ATTENTION COLLAPSE =============================
    for (int idx = tid; idx < 1024; idx += NTHR) {
        int i = idx >> 5, g = idx & 31;
        float a = 0.f;
        #pragma unroll
        for (int j = 0; j < 32; j++) a = fmaf(Cm[i * 32 + j], wk[g * 32 + j], a);
        T1f[i * 32 + g] = a;
    }
    __syncthreads();
    const float rsL = rsqrtf((float)LT);
    for (int idx = tid; idx < 1024; idx += NTHR) {
        int h = idx >> 5, g = idx & 31;
        float a = 0.f;
        #pragma unroll
        for (int i = 0; i < 32; i++) a = fmaf(wq[h * 32 + i], T1f[i * 32 + g], a);
        T2f[h * 32 + g] = a * rsL;
    }
    __syncthreads();
    if (tid < 32) {
        float mx = -1e30f;
        #pragma unroll
        for (int g = 0; g < 32; g++) mx = fmaxf(mx, T2f[tid * 32 + g]);
        float s = 0.f;
        #pragma unroll
        for (int g = 0; g < 32; g++) {
            float e = __expf(T2f[tid * 32 + g] - mx);
            T2f[tid * 32 + g] = e; s += e;
        }
        float inv = 1.f / s;
        #pragma unroll
        for (int g = 0; g < 32; g++) T2f[tid * 32 + g] *= inv;
    }
    __syncthreads();
    for (int idx = tid; idx < 1024; idx += NTHR) {
        int h = idx >> 5, j = idx & 31;
        float a = 0.f;
        #pragma unroll
        for (int g = 0; g < 32; g++) a = fmaf(T2f[h * 32 + g], wv[g * 32 + j], a);
        T1f[h * 32 + j] = a;
    }
    __syncthreads();
    for (int idx = tid; idx < 1024; idx += NTHR) {
        int o = idx >> 5, j = idx & 31;
        float a = 0.f;
        #pragma unroll
        for (int h = 0; h < 32; h++) a = fmaf(wo[o * 32 + h], T1f[h * 32 + j], a);
        Wbb[o * 32 + j] = f2bf(a + (o == j ? 1.f : 0.f));    // Wb + I
    }
    __syncthreads();

    // =================== PIPELINE: register-chained MFMAs ===============
    svec8 wbf0 = *(const svec8*)&Wbb[Lr0 * 32 + Q * 8];
    svec8 wbf1 = *(const svec8*)&Wbb[Lr1 * 32 + Q * 8];
    svec8 a1f0, a1f1, a2f0, a2f1, a3f0, a3f1;
    #pragma unroll
    for (int j = 0; j < 8; j++) {
        a1f0[j] = (short)f2bf(f1w1[Lr0 * 32 + Q * 8 + j]);
        a1f1[j] = (short)f2bf(f1w1[Lr1 * 32 + Q * 8 + j]);
        a2f0[j] = (short)f2bf(f1w2[Lr0 * 32 + Q * 8 + j]);
        a2f1[j] = (short)f2bf(f1w2[Lr1 * 32 + Q * 8 + j]);
        a3f0[j] = (short)f2bf(f2w1[Lr0 * 32 + Q * 8 + j]);
        a3f1[j] = (short)f2bf(f2w1[Lr1 * 32 + Q * 8 + j]);
    }
    unsigned pg1[4], pb1[4], pg2[4], pb2[4], pc1[4], pc2[4], pc3[4], pw2[4];
    #pragma unroll
    for (int i = 0; i < 4; i++) {
        int f = Q * 8 + 2 * i;
        pg1[i] = pk2(ln1g[f], ln1g[f + 1]);
        pb1[i] = pk2(ln1b[f], ln1b[f + 1]);
        pg2[i] = pk2(ln2g[f], ln2g[f + 1]);
        pb2[i] = pk2(ln2b[f], ln2b[f + 1]);
        pc1[i] = pk2(f1b1[f], f1b1[f + 1]);
        pc2[i] = pk2(f1b2[f], f1b2[f + 1]);
        pc3[i] = pk2(f2b1[f], f2b1[f + 1]);
        pw2[i] = pk2(f2w2[f], f2w2[f + 1]);
    }
    const float ybias = f2b2[0];

    float s0 = 0.f, s1 = 0.f, s2 = 0.f;
    for (int t = w; t < NTILE; t += NW) {
        const int tb = (t * 2 + (tk >> 3)) ^ Q;
        const int bo = tk & 7;
        svec8 bx;
        float xf[8];
        #pragma unroll
        for (int j = 0; j < 8; j++) {
            unsigned short v = XT[((Q * 8 + j) * 93 + tb) * 8 + bo];
            bx[j] = (short)v;
            xf[j] = bf2f(v);
        }
        fvec4 d0 = __builtin_amdgcn_mfma_f32_16x16x32_bf16(wbf0, bx, zc, 0,0,0);
        fvec4 d1 = __builtin_amdgcn_mfma_f32_16x16x32_bf16(wbf1, bx, zc, 0,0,0);
        // LN1: feats are in-lane (8) x cross-quad (x4 via shfl 16/32)
        float v[8];
        #pragma unroll
        for (int j = 0; j < 4; j++) { v[j] = d0[j]; v[4 + j] = d1[j]; }
        float S = 0.f;
        #pragma unroll
        for (int j = 0; j < 8; j++) S += v[j];
        S += __shfl_xor(S, 16); S += __shfl_xor(S, 32);
        float mean = S * (1.f / 32.f);
        float vs = 0.f;
        #pragma unroll
        for (int j = 0; j < 8; j++) { float d = v[j] - mean; vs = fmaf(d, d, vs); }
        vs += __shfl_xor(vs, 16); vs += __shfl_xor(vs, 32);
        float rs = rsqrtf(vs * (1.f / 32.f) + 1e-5f);
        svec8 tf;
        #pragma unroll
        for (int j = 0; j < 8; j++)
            tf[j] = (short)f2bf((v[j] - mean) * rs * pget(pg1, j) + pget(pb1, j));
        fvec4 u0 = __builtin_amdgcn_mfma_f32_16x16x32_bf16(a1f0, tf, zc, 0,0,0);
        fvec4 u1 = __builtin_amdgcn_mfma_f32_16x16x32_bf16(a1f1, tf, zc, 0,0,0);
        svec8 uf;
        #pragma unroll
        for (int j = 0; j < 4; j++) {
            uf[j]   = (short)f2bf(fmaxf(u0[j] + pget(pc1, j), 0.f));
            uf[4+j] = (short)f2bf(fmaxf(u1[j] + pget(pc1, 4 + j), 0.f));
        }
        fvec4 g0 = __builtin_amdgcn_mfma_f32_16x16x32_bf16(a2f0, uf, zc, 0,0,0);
        fvec4 g1 = __builtin_amdgcn_mfma_f32_16x16x32_bf16(a2f1, uf, zc, 0,0,0);
        // + f1b2 + residual x, LN2
        #pragma unroll
        for (int j = 0; j < 8; j++)
            v[j] = (j < 4 ? g0[j] : g1[j - 4]) + pget(pc2, j) + xf[j];
        float S2 = 0.f;
        #pragma unroll
        for (int j = 0; j < 8; j++) S2 += v[j];
        S2 += __shfl_xor(S2, 16); S2 += __shfl_xor(S2, 32);
        float mean2 = S2 * (1.f / 32.f);
        float vs2 = 0.f;
        #pragma unroll
        for (int j = 0; j < 8; j++) { float d = v[j] - mean2; vs2 = fmaf(d, d, vs2); }
        vs2 += __shfl_xor(vs2, 16); vs2 += __shfl_xor(vs2, 32);
        float rs2 = rsqrtf(vs2 * (1.f / 32.f) + 1e-5f);
        svec8 t2;
        #pragma unroll
        for (int j = 0; j < 8; j++)
            t2[j] = (short)f2bf((v[j] - mean2) * rs2 * pget(pg2, j) + pget(pb2, j));
        fvec4 e0 = __builtin_amdgcn_mfma_f32_16x16x32_bf16(a3f0, t2, zc, 0,0,0);
        fvec4 e1 = __builtin_amdgcn_mfma_f32_16x16x32_bf16(a3f1, t2, zc, 0,0,0);
        float yp = 0.f;
        #pragma unroll
        for (int j = 0; j < 8; j++) {
            float e = (j < 4 ? e0[j] : e1[j - 4]) + pget(pc3, j);
            yp = fmaf(pget(pw2, j), fmaxf(e, 0.f), yp);
        }
        yp += __shfl_xor(yp, 16); yp += __shfl_xor(yp, 32);
        if (Q == 0) {
            int tok = t * 16 + tk;
            float yv = yp + ybias;
            if (tok < L0T)            s0 += yv;
            else if (tok < LT - 1)    s1 += yv;
            else if (tok == LT - 1)   s2 += yv;
        }
    }

    // wave reduce over lanes 0..15 (only Q==0 lanes carry values)
    s0 += __shfl_xor(s0, 1); s0 += __shfl_xor(s0, 2);
    s0 += __shfl_xor(s0, 4); s0 += __shfl_xor(s0, 8);
    s1 += __shfl_xor(s1, 1); s1 += __shfl_xor(s1, 2);
    s1 += __shfl_xor(s1, 4); s1 += __shfl_xor(s1, 8);
    s2 += __shfl_xor(s2, 1); s2 += __shfl_xor(s2, 2);
    s2 += __shfl_xor(s2, 4); s2 += __shfl_xor(s2, 8);
    if (ln == 0) { red[w * 3] = s0; red[w * 3 + 1] = s1; red[w * 3 + 2] = s2; }
    __syncthreads();
    if (tid == 0) {
        float a0 = 0.f, a1 = 0.f, a2 = 0.f;
        #pragma unroll
        for (int k = 0; k < NW; k++) {
            a0 += red[k * 3]; a1 += red[k * 3 + 1]; a2 += red[k * 3 + 2];
        }
        out[b] = a0 / (float)L0T + a1 / (float)L1T + a2;
    }
}

extern "C" void kernel_launch(void* const* d_in, const int* in_sizes, int n_in,
                              void* d_out, int out_size, void* d_ws, size_t ws_size,
                              hipStream_t stream)
{
    const float* x0   = (const float*)d_in[0];
    const float* x1   = (const float*)d_in[1];
    const float* pos0 = (const float*)d_in[2];
    const float* pos1 = (const float*)d_in[3];
    const float* xcT  = (const float*)d_in[4];
    const float* e0w1 = (const float*)d_in[5];
    const float* e0b1 = (const float*)d_in[6];
    const float* e0w2 = (const float*)d_in[7];
    const float* e0b2 = (const float*)d_in[8];
    const float* e1w1 = (const float*)d_in[9];
    const float* e1b1 = (const float*)d_in[10];
    const float* e1w2 = (const float*)d_in[11];
    const float* e1b2 = (const float*)d_in[12];
    const float* ecw1 = (const float*)d_in[13];
    const float* ecb1 = (const float*)d_in[14];
    const float* ecw2 = (const float*)d_in[15];
    const float* ecb2 = (const float*)d_in[16];
    const float* wq   = (const float*)d_in[17];
    const float* wk   = (const float*)d_in[18];
    const float* wv   = (const float*)d_in[19];
    const float* wo   = (const float*)d_in[20];
    const float* ln1g = (const float*)d_in[21];
    const float* ln1b = (const float*)d_in[22];
    const float* ln2g = (const float*)d_in[23];
    const float* ln2b = (const float*)d_in[24];
    const float* f1w1 = (const float*)d_in[25];
    const float* f1b1 = (const float*)d_in[26];
    const float* f1w2 = (const float*)d_in[27];
    const float* f1b2 = (const float*)d_in[28];
    const float* f2w1 = (const float*)d_in[29];
    const float* f2b1 = (const float*)d_in[30];
    const float* f2w2 = (const float*)d_in[31];
    const float* f2b2 = (const float*)d_in[32];
    float* out = (float*)d_out;

    const int B = in_sizes[0] / (L0T * 8);

    hipLaunchKernelGGL(fused_kernel, dim3(B), dim3(NTHR), 0, stream,
                       x0, x1, pos0, pos1, xcT,
                       e0w1, e0b1, e0w2, e0b2, e1w1, e1b1, e1w2, e1b2,
                       ecw1, ecb1, ecw2, ecb2, wq, wk, wv, wo,
                       ln1g, ln1b, ln2g, ln2b,
                       f1w1, f1b1, f1w2, f1b2, f2w1, f2b1, f2w2, f2b2,
                       out);
}